// Round 1
// baseline (129.916 us; speedup 1.0000x reference)
//
#include <hip/hip_runtime.h>
#include <hip/hip_fp16.h>

#define N_NODES 100000
#define N_EDGES 600000
#define DIM 128
#define HID 64

typedef __attribute__((ext_vector_type(8))) _Float16 half8;
typedef __attribute__((ext_vector_type(4))) float floatx4;

// ---------------------------------------------------------------------------
// Kernel 1: P[n][0:64]  = node_emb[n] @ W1[0:128]   + b1   (src partial)
//           P[n][64:128]= node_emb[n] @ W1[128:256]        (dst partial)
// f16 MFMA 16x16x32, fp32 accumulate, store P as f16.
// ---------------------------------------------------------------------------
__global__ __launch_bounds__(256) void precompute_P(
    const float* __restrict__ node_emb,
    const float* __restrict__ W1,
    const float* __restrict__ b1,
    __half* __restrict__ P)
{
    // B' in LDS, column-major with pad: Bs[n][k], n = output col (0..127),
    // k = reduction idx (0..127). Row stride 136 f16 (=272 B) to spread banks.
    __shared__ alignas(16) _Float16 Bs[128][136];
    const int tid = threadIdx.x;

    for (int i = tid; i < 128 * 128; i += 256) {
        const int n = i >> 7;
        const int k = i & 127;
        const float w = (n < HID) ? W1[k * HID + n]
                                  : W1[(DIM + k) * HID + (n - HID)];
        Bs[n][k] = (_Float16)w;
    }
    __syncthreads();

    const int wid  = tid >> 6;
    const int lane = tid & 63;
    const int m0 = blockIdx.x * 64 + wid * 16;
    if (m0 >= N_NODES) return;

    const int r  = m0 + (lane & 15);
    const int rc = (r < N_NODES) ? r : (N_NODES - 1);   // clamp for loads
    const float* arow = node_emb + (size_t)rc * DIM;
    const int kq = (lane >> 4) * 8;                      // 0,8,16,24

    floatx4 acc[8];
#pragma unroll
    for (int nt = 0; nt < 8; nt++) acc[nt] = (floatx4){0.f, 0.f, 0.f, 0.f};

#pragma unroll
    for (int ks = 0; ks < 4; ks++) {
        const int k0 = ks * 32 + kq;
        const float4 a0 = *(const float4*)(arow + k0);
        const float4 a1 = *(const float4*)(arow + k0 + 4);
        half8 af;
        af[0] = (_Float16)a0.x; af[1] = (_Float16)a0.y;
        af[2] = (_Float16)a0.z; af[3] = (_Float16)a0.w;
        af[4] = (_Float16)a1.x; af[5] = (_Float16)a1.y;
        af[6] = (_Float16)a1.z; af[7] = (_Float16)a1.w;
#pragma unroll
        for (int nt = 0; nt < 8; nt++) {
            const half8 bf = *(const half8*)&Bs[nt * 16 + (lane & 15)][k0];
            acc[nt] = __builtin_amdgcn_mfma_f32_16x16x32_f16(af, bf, acc[nt], 0, 0, 0);
        }
    }

    // C/D layout (16x16): col = lane&15, row = (lane>>4)*4 + reg
    const int crow = (lane >> 4) * 4;
    const int ccol = lane & 15;
#pragma unroll
    for (int nt = 0; nt < 8; nt++) {
        const int col  = nt * 16 + ccol;
        const float bias = (col < HID) ? b1[col] : 0.f;
#pragma unroll
        for (int i = 0; i < 4; i++) {
            const int gr = m0 + crow + i;
            if (gr < N_NODES)
                P[(size_t)gr * 128 + col] = __float2half(acc[nt][i] + bias);
        }
    }
}

// ---------------------------------------------------------------------------
// Detect whether edge_index is stored as int64 (odd 32-bit words all zero) or
// int32. Uniform, deterministic, ~16 scalar loads.
// ---------------------------------------------------------------------------
__device__ inline bool detect_int64(const int* e32) {
    int orv = 0;
#pragma unroll
    for (int k = 0; k < 8; k++) orv |= e32[2 * k + 1];
    return orv == 0;
}

// ---------------------------------------------------------------------------
// Kernel 2: one wave per edge. lane j in 0..63:
//   h_j = relu(P[src][j] + P[dst][64+j]); logit = sum_j h_j * W2[j] + b2
// ---------------------------------------------------------------------------
__global__ __launch_bounds__(256) void edge_mlp(
    const __half* __restrict__ P,
    const void* __restrict__ eidx_raw,
    const float* __restrict__ W2,
    const float* __restrict__ b2,
    float* __restrict__ out)
{
    const int* e32 = (const int*)eidx_raw;
    const long long* e64 = (const long long*)eidx_raw;
    const bool is64 = detect_int64(e32);

    const int lane = threadIdx.x & 63;
    const float w2  = W2[lane];
    const float b2v = b2[0];

    const int gwid   = (int)((blockIdx.x * blockDim.x + threadIdx.x) >> 6);
    const int nwaves = (int)((gridDim.x * blockDim.x) >> 6);

    for (int e0 = gwid * 4; e0 < N_EDGES; e0 += nwaves * 4) {
        float res[4];
#pragma unroll
        for (int u = 0; u < 4; u++) {
            const int e = e0 + u;
            int s, d;
            if (is64) { s = (int)e64[e]; d = (int)e64[N_EDGES + e]; }
            else      { s = e32[e];      d = e32[N_EDGES + e]; }
            const float a  = __half2float(P[(size_t)s * 128 + lane]);
            const float bb = __half2float(P[(size_t)d * 128 + 64 + lane]);
            float t = fmaxf(a + bb, 0.f) * w2;
#pragma unroll
            for (int off = 32; off >= 1; off >>= 1)
                t += __shfl_xor(t, off, 64);
            res[u] = t + b2v;
        }
        if (lane == 0)
            *(float4*)(out + e0) = make_float4(res[0], res[1], res[2], res[3]);
    }
}

// ---------------------------------------------------------------------------
// Fallback (only if ws too small): direct per-edge compute, slow but correct.
// ---------------------------------------------------------------------------
__global__ __launch_bounds__(256) void edge_mlp_direct(
    const float* __restrict__ node_emb,
    const void* __restrict__ eidx_raw,
    const float* __restrict__ W1,
    const float* __restrict__ b1,
    const float* __restrict__ W2,
    const float* __restrict__ b2,
    float* __restrict__ out)
{
    const int* e32 = (const int*)eidx_raw;
    const long long* e64 = (const long long*)eidx_raw;
    const bool is64 = detect_int64(e32);

    const int lane = threadIdx.x & 63;
    const float w2  = W2[lane];
    const float b2v = b2[0];
    const int gwid   = (int)((blockIdx.x * blockDim.x + threadIdx.x) >> 6);
    const int nwaves = (int)((gridDim.x * blockDim.x) >> 6);

    for (int e = gwid; e < N_EDGES; e += nwaves) {
        int s, d;
        if (is64) { s = (int)e64[e]; d = (int)e64[N_EDGES + e]; }
        else      { s = e32[e];      d = e32[N_EDGES + e]; }
        const float* es = node_emb + (size_t)s * DIM;
        const float* ed = node_emb + (size_t)d * DIM;
        float acc = b1[lane];
        for (int k = 0; k < DIM; k++) {
            acc += es[k] * W1[k * HID + lane];
            acc += ed[k] * W1[(DIM + k) * HID + lane];
        }
        float t = fmaxf(acc, 0.f) * w2;
#pragma unroll
        for (int off = 32; off >= 1; off >>= 1)
            t += __shfl_xor(t, off, 64);
        if (lane == 0) out[e] = t + b2v;
    }
}

// ---------------------------------------------------------------------------
extern "C" void kernel_launch(void* const* d_in, const int* in_sizes, int n_in,
                              void* d_out, int out_size, void* d_ws, size_t ws_size,
                              hipStream_t stream) {
    const float* node_emb = (const float*)d_in[0];
    const void*  eidx     = d_in[1];
    const float* W1       = (const float*)d_in[2];
    const float* b1       = (const float*)d_in[3];
    const float* W2       = (const float*)d_in[4];
    const float* b2       = (const float*)d_in[5];
    float* out = (float*)d_out;

    const size_t pbytes = (size_t)N_NODES * 128 * sizeof(__half);
    if (ws_size >= pbytes) {
        __half* P = (__half*)d_ws;
        precompute_P<<<(N_NODES + 63) / 64, 256, 0, stream>>>(node_emb, W1, b1, P);
        edge_mlp<<<2048, 256, 0, stream>>>(P, eidx, W2, b2, out);
    } else {
        edge_mlp_direct<<<4096, 256, 0, stream>>>(node_emb, eidx, W1, b1, W2, b2, out);
    }
}

// Round 2
// 59.807 us; speedup vs baseline: 2.1723x; 2.1723x over previous
//
#include <hip/hip_runtime.h>
#include <hip/hip_fp16.h>

#define N_NODES 100000
#define N_EDGES 600000
#define DIM 128
#define HID 64
#define TILES_TOTAL (N_NODES / 16)   // 6250, exact

typedef __attribute__((ext_vector_type(8))) _Float16 half8;
typedef __attribute__((ext_vector_type(4))) float floatx4;

// ---------------------------------------------------------------------------
// Kernel 1: P[n][c] = node_emb[n] @ Wbig[:,c] (+ b1[c] for c<64)
//   Wbig[k][c] = c<64 ? W1[k][c] : W1[128+k][c-64]     (k,c in 0..127)
// Persistent blocks; W1^T staged to LDS once per block; B fragments held in
// registers (64 VGPR) so the tile loop is pure {global A read, MFMA, store}.
// ---------------------------------------------------------------------------
__global__ __launch_bounds__(256) void precompute_P(
    const float* __restrict__ node_emb,
    const float* __restrict__ W1,
    const float* __restrict__ b1,
    __half* __restrict__ P)
{
    __shared__ alignas(16) _Float16 W1T[128][136];   // [c][k], row 272 B
    const int tid = threadIdx.x;

    // Stage W1^T as f16: thread handles (c, 8-wide k chunk); ds_write_b128.
    for (int i = tid; i < 128 * 16; i += 256) {
        const int c  = i >> 4;
        const int kb = (i & 15) * 8;
        half8 h;
#pragma unroll
        for (int j = 0; j < 8; j++) {
            const int k = kb + j;
            const float w = (c < HID) ? W1[k * HID + c]
                                      : W1[(DIM + k) * HID + (c - HID)];
            h[j] = (_Float16)w;
        }
        *(half8*)&W1T[c][kb] = h;
    }
    __syncthreads();

    const int wid  = tid >> 6;
    const int lane = tid & 63;
    const int lr   = lane & 15;          // A row offset / C col offset
    const int kq   = (lane >> 4) * 8;    // k sub-block

    // B fragments -> registers (wave-invariant across all row tiles).
    half8 bfr[8][4];
#pragma unroll
    for (int nt = 0; nt < 8; nt++)
#pragma unroll
        for (int ks = 0; ks < 4; ks++)
            bfr[nt][ks] = *(const half8*)&W1T[nt * 16 + lr][ks * 32 + kq];

    float bias[8];
#pragma unroll
    for (int nt = 0; nt < 8; nt++) {
        const int col = nt * 16 + lr;
        bias[nt] = (col < HID) ? b1[col] : 0.f;
    }

    const int nwaves = (int)(gridDim.x * 4);
    const int gw     = (int)(blockIdx.x * 4 + wid);
    const int crow   = (lane >> 4) * 4;

    for (int t = gw; t < TILES_TOTAL; t += nwaves) {
        const float* arow = node_emb + (size_t)(t * 16 + lr) * DIM + kq;
        float4 a[4][2];
#pragma unroll
        for (int ks = 0; ks < 4; ks++) {
            a[ks][0] = *(const float4*)(arow + ks * 32);
            a[ks][1] = *(const float4*)(arow + ks * 32 + 4);
        }
        floatx4 acc[8];
#pragma unroll
        for (int nt = 0; nt < 8; nt++) acc[nt] = (floatx4){0.f, 0.f, 0.f, 0.f};
#pragma unroll
        for (int ks = 0; ks < 4; ks++) {
            half8 af;
            af[0] = (_Float16)a[ks][0].x; af[1] = (_Float16)a[ks][0].y;
            af[2] = (_Float16)a[ks][0].z; af[3] = (_Float16)a[ks][0].w;
            af[4] = (_Float16)a[ks][1].x; af[5] = (_Float16)a[ks][1].y;
            af[6] = (_Float16)a[ks][1].z; af[7] = (_Float16)a[ks][1].w;
#pragma unroll
            for (int nt = 0; nt < 8; nt++)
                acc[nt] = __builtin_amdgcn_mfma_f32_16x16x32_f16(af, bfr[nt][ks], acc[nt], 0, 0, 0);
        }
        __half* prow = P + (size_t)(t * 16) * 128;
#pragma unroll
        for (int nt = 0; nt < 8; nt++) {
            const int col = nt * 16 + lr;
#pragma unroll
            for (int i = 0; i < 4; i++)
                prow[(size_t)(crow + i) * 128 + col] = __float2half(acc[nt][i] + bias[nt]);
        }
    }
}

// ---------------------------------------------------------------------------
__device__ inline bool detect_int64(const int* e32) {
    int orv = 0;
#pragma unroll
    for (int k = 0; k < 8; k++) orv |= e32[2 * k + 1];
    return orv == 0;
}

// ---------------------------------------------------------------------------
// Kernel 2: half-wave per edge, half2 lanes.
//   lanes 0-31: edge e (sub=0); lanes 32-63: edge e+1 (sub=1)
//   lane j2 handles h[2*j2], h[2*j2+1]; 5-deep xor reduce within 32 lanes.
// ---------------------------------------------------------------------------
__global__ __launch_bounds__(256) void edge_mlp(
    const __half* __restrict__ P,
    const void* __restrict__ eidx_raw,
    const float* __restrict__ W2,
    const float* __restrict__ b2,
    float* __restrict__ out)
{
    const int* e32 = (const int*)eidx_raw;
    const long long* e64 = (const long long*)eidx_raw;
    const bool is64 = detect_int64(e32);

    const int tid  = threadIdx.x;
    const int lane = tid & 63;
    const int sub  = lane >> 5;
    const int j2   = lane & 31;
    const float2 w2 = *(const float2*)(W2 + 2 * j2);
    const float b2v = b2[0];
    const __half2* P2 = (const __half2*)P;   // rows of 64 half2

    const int gwid   = (int)((blockIdx.x * blockDim.x + tid) >> 6);
    const int nwaves = (int)((gridDim.x * blockDim.x) >> 6);

    for (int base = gwid * 8; base < N_EDGES; base += nwaves * 8) {
        int s[4], d[4];
#pragma unroll
        for (int u = 0; u < 4; u++) {
            const int e = base + 2 * u + sub;
            if (is64) { s[u] = (int)e64[e]; d[u] = (int)e64[N_EDGES + e]; }
            else      { s[u] = e32[e];      d[u] = e32[N_EDGES + e]; }
        }
        __half2 av[4], bv[4];
#pragma unroll
        for (int u = 0; u < 4; u++) {
            av[u] = P2[(size_t)s[u] * 64 + j2];
            bv[u] = P2[(size_t)d[u] * 64 + 32 + j2];
        }
#pragma unroll
        for (int u = 0; u < 4; u++) {
            const float2 a = __half22float2(av[u]);
            const float2 b = __half22float2(bv[u]);
            float t = fmaxf(a.x + b.x, 0.f) * w2.x
                    + fmaxf(a.y + b.y, 0.f) * w2.y;
#pragma unroll
            for (int off = 16; off >= 1; off >>= 1)
                t += __shfl_xor(t, off, 64);
            const float o1 = __shfl(t, 32, 64);
            if (lane == 0)
                *(float2*)(out + base + 2 * u) = make_float2(t + b2v, o1 + b2v);
        }
    }
}

// ---------------------------------------------------------------------------
// Fallback (ws too small): direct per-edge compute, slow but correct.
// ---------------------------------------------------------------------------
__global__ __launch_bounds__(256) void edge_mlp_direct(
    const float* __restrict__ node_emb,
    const void* __restrict__ eidx_raw,
    const float* __restrict__ W1,
    const float* __restrict__ b1,
    const float* __restrict__ W2,
    const float* __restrict__ b2,
    float* __restrict__ out)
{
    const int* e32 = (const int*)eidx_raw;
    const long long* e64 = (const long long*)eidx_raw;
    const bool is64 = detect_int64(e32);

    const int lane = threadIdx.x & 63;
    const float w2  = W2[lane];
    const float b2v = b2[0];
    const int gwid   = (int)((blockIdx.x * blockDim.x + threadIdx.x) >> 6);
    const int nwaves = (int)((gridDim.x * blockDim.x) >> 6);

    for (int e = gwid; e < N_EDGES; e += nwaves) {
        int s, d;
        if (is64) { s = (int)e64[e]; d = (int)e64[N_EDGES + e]; }
        else      { s = e32[e];      d = e32[N_EDGES + e]; }
        const float* es = node_emb + (size_t)s * DIM;
        const float* ed = node_emb + (size_t)d * DIM;
        float acc = b1[lane];
        for (int k = 0; k < DIM; k++) {
            acc += es[k] * W1[k * HID + lane];
            acc += ed[k] * W1[(DIM + k) * HID + lane];
        }
        float t = fmaxf(acc, 0.f) * w2;
#pragma unroll
        for (int off = 32; off >= 1; off >>= 1)
            t += __shfl_xor(t, off, 64);
        if (lane == 0) out[e] = t + b2v;
    }
}

// ---------------------------------------------------------------------------
extern "C" void kernel_launch(void* const* d_in, const int* in_sizes, int n_in,
                              void* d_out, int out_size, void* d_ws, size_t ws_size,
                              hipStream_t stream) {
    const float* node_emb = (const float*)d_in[0];
    const void*  eidx     = d_in[1];
    const float* W1       = (const float*)d_in[2];
    const float* b1       = (const float*)d_in[3];
    const float* W2       = (const float*)d_in[4];
    const float* b2       = (const float*)d_in[5];
    float* out = (float*)d_out;

    const size_t pbytes = (size_t)N_NODES * 128 * sizeof(__half);
    if (ws_size >= pbytes) {
        __half* P = (__half*)d_ws;
        precompute_P<<<512, 256, 0, stream>>>(node_emb, W1, b1, P);
        edge_mlp<<<2048, 256, 0, stream>>>(P, eidx, W2, b2, out);
    } else {
        edge_mlp_direct<<<4096, 256, 0, stream>>>(node_emb, eidx, W1, b1, W2, b2, out);
    }
}